// Round 19
// baseline (3183.314 us; speedup 1.0000x reference)
//
#include <hip/hip_runtime.h>
#include <hip/hip_bf16.h>

#define VOCAB 50000
#define EMB   300
#define HID   1024
#define TT    512
#define BB    64

// Block layout for pre/h: [t][kb=64][row=64][c=16] bf16; slab = 65536 shorts.
// h1/h2 are 2-slab rings (slab = t&1).
//
// Pipelined scan, 32-col WGs: 64 WGs total.
//   WGs 0..31  (L=0): cols 32bx..32bx+31. h1[t]=tanh(pre0+h1[t-1]Whh0^T+bhh0);
//     FUSE: pre1[t-1] = h1[t-1]*Wih1^T+bih1 (2nd MFMA chain, same A frags).
//   WGs 32..63 (L=1): h2[t]=tanh(pre1[t]+h2[t-1]Whh1^T+bhh1), step t gated on
//     flagsA[bx] >= t+2 -- 1:1 producer (L0 WG bx owns exactly its pre1 cols).
// Halving WG count (16->32 cols) halves the per-step device-scope h-broadcast
// (16 MB -> 8 MB), the suspected fabric-BW limiter; per-WG A pattern is
// IDENTICAL to the verified 2404us kernel.
//
// Flags: 64B stride, s_sleep poll backoff (verified +16% in round 18).
// NOTE: asm "=v" load results never live across a variable-trip loop.

typedef __attribute__((ext_vector_type(8))) short short8;
typedef __attribute__((ext_vector_type(4))) float floatx4;

__device__ inline float b2f(unsigned int u) {
    union { unsigned int i; float f; } v; v.i = u << 16; return v.f;
}
__device__ inline unsigned short f2b(float f) {
    __hip_bfloat16 h = __float2bfloat16(f);
    return *reinterpret_cast<unsigned short*>(&h);
}

#define WAIT_VM16(N, A) asm volatile("s_waitcnt vmcnt(" #N ")"              \
    : "+v"((A)[0]), "+v"((A)[1]), "+v"((A)[2]), "+v"((A)[3]),               \
      "+v"((A)[4]), "+v"((A)[5]), "+v"((A)[6]), "+v"((A)[7]),               \
      "+v"((A)[8]), "+v"((A)[9]), "+v"((A)[10]), "+v"((A)[11]),             \
      "+v"((A)[12]), "+v"((A)[13]), "+v"((A)[14]), "+v"((A)[15])            \
    :: "memory")

#define WAIT_PR8(P) asm volatile("s_waitcnt vmcnt(0)"                        \
    : "+v"((P)[0]), "+v"((P)[1]), "+v"((P)[2]), "+v"((P)[3]),               \
      "+v"((P)[4]), "+v"((P)[5]), "+v"((P)[6]), "+v"((P)[7]) :: "memory")

// Per-wave mode probe (W >= 2048 shorts): bf16 weights in (-0.5,0.5).
__device__ inline int detect_mode256(const void* W, int tid, int* modeSh)
{
    const unsigned short* p = (const unsigned short*)W;
    int bad = 0;
    for (int i = tid; i < 1024; i += 256) {
        float v = b2f(p[2 * i]);
        if (!(v > -0.5f && v < 0.5f)) bad++;
    }
    for (int off = 32; off; off >>= 1) bad += __shfl_down(bad, off);
    if ((tid & 63) == 0) modeSh[tid >> 6] = bad;
    return 0;
}

// ---------------------------------------------------------------------------
// proj: pre0[t*64+b][n] = bf16( emb[x[b][t]]·W_ih0^T + b_ih0 ), block layout.
// One WG per t: emb rows staged once, col-blocks looped. WG 0 zeroes flags.
// (verbatim from verified 2404us kernel)
// ---------------------------------------------------------------------------
__global__ __launch_bounds__(256)
void proj_kernel(const int*  __restrict__ xidx,
                 const void* __restrict__ emb,
                 const void* __restrict__ W,
                 const void* __restrict__ bias,
                 unsigned short* __restrict__ C,    // block layout bf16
                 int* __restrict__ ctl)
{
    const int t   = blockIdx.x;
    const int tid = threadIdx.x;
    __shared__ unsigned short eT[64 * 328];          // 41984 B
    __shared__ unsigned short Wl[16 * 328];          // 10496 B
    __shared__ __align__(16) unsigned short oT[1024];// 2 KB
    __shared__ int xqL[64];
    __shared__ int modeSh[4];

    if (t == 0) {   // zero both flag regions
        for (int i = 64 + tid; i < 64 + 2048; i += 256) ctl[i] = 0;
    }
    if (tid < 64) xqL[tid] = xidx[tid * TT + t];
    for (int i = tid; i < 64 * 28; i += 256) {       // zero eT pad
        int b = i / 28, c = 300 + i % 28;
        eT[b * 328 + c] = 0;
    }
    for (int i = tid; i < 16 * 28; i += 256) {       // zero Wl pad
        int nl = i / 28, c = 300 + i % 28;
        Wl[nl * 328 + c] = 0;
    }
    detect_mode256(W, tid, modeSh);
    __syncthreads();
    const int mode = (modeSh[0] + modeSh[1] + modeSh[2] + modeSh[3]) > 16;

    if (mode) {
        for (int i = tid; i < 64 * 75; i += 256) {
            int b = i / 75, seg = i % 75;
            const float* src = (const float*)emb
                             + (size_t)xqL[b] * EMB + seg * 4;
            float4 f = *(const float4*)src;
            unsigned short* d = &eT[b * 328 + seg * 4];
            d[0] = f2b(f.x); d[1] = f2b(f.y); d[2] = f2b(f.z); d[3] = f2b(f.w);
        }
    } else {
        for (int i = tid; i < 64 * 75; i += 256) {
            int b = i / 75, seg = i % 75;
            const unsigned short* src = (const unsigned short*)emb
                                      + (size_t)xqL[b] * EMB + seg * 4;
            *(uint2*)&eT[b * 328 + seg * 4] = *(const uint2*)src;
        }
    }

    const int wave = tid >> 6, lane = tid & 63;
    const int quad = lane >> 4, ln = lane & 15;

    for (int nb = 0; nb < 64; ++nb) {
        __syncthreads();
        if (mode) {
            const float* Wf = (const float*)W;
            for (int i = tid; i < 16 * 75; i += 256) {
                int nl = i / 75, seg = i % 75;
                float4 f = *(const float4*)(Wf + (size_t)(nb * 16 + nl) * EMB + seg * 4);
                unsigned short* d = &Wl[nl * 328 + seg * 4];
                d[0] = f2b(f.x); d[1] = f2b(f.y); d[2] = f2b(f.z); d[3] = f2b(f.w);
            }
        } else {
            const unsigned short* Wb = (const unsigned short*)W;
            for (int i = tid; i < 16 * 75; i += 256) {
                int nl = i / 75, seg = i % 75;
                *(uint2*)&Wl[nl * 328 + seg * 4] =
                    *(const uint2*)(Wb + (size_t)(nb * 16 + nl) * EMB + seg * 4);
            }
        }
        __syncthreads();

        floatx4 acc = {0.f, 0.f, 0.f, 0.f};
        #pragma unroll
        for (int kk = 0; kk < 10; ++kk) {
            int k = kk * 32 + quad * 8;
            short8 a = *(const short8*)&eT[(wave * 16 + ln) * 328 + k];
            short8 b = *(const short8*)&Wl[ln * 328 + k];
            acc = __builtin_amdgcn_mfma_f32_16x16x32_bf16(a, b, acc, 0, 0, 0);
        }
        const int col = nb * 16 + ln;
        const float bvf = mode ? ((const float*)bias)[col]
                               : b2f(((const unsigned short*)bias)[col]);
        oT[(wave * 16 + quad * 4 + 0) * 16 + ln] = f2b(acc[0] + bvf);
        oT[(wave * 16 + quad * 4 + 1) * 16 + ln] = f2b(acc[1] + bvf);
        oT[(wave * 16 + quad * 4 + 2) * 16 + ln] = f2b(acc[2] + bvf);
        oT[(wave * 16 + quad * 4 + 3) * 16 + ln] = f2b(acc[3] + bvf);
        __syncthreads();
        if (tid < 128) {
            short8 hv = *(const short8*)&oT[tid * 8];
            *(short8*)(C + ((size_t)t * 64 + nb) * 1024 + tid * 8) = hv;
        }
    }
}

// ---------------------------------------------------------------------------
// scan2: 64 WGs x 256 thr, 32 cols per WG.
// ---------------------------------------------------------------------------
__global__ __launch_bounds__(256, 1)
void scan2_kernel(unsigned short* __restrict__ preB,   // block layout bf16
                  unsigned short* __restrict__ h1B,    // 2-slab ring
                  unsigned short* __restrict__ h2B,    // 2-slab ring
                  const void* __restrict__ Whh0, const void* __restrict__ bhh0,
                  const void* __restrict__ Wih1, const void* __restrict__ bih1,
                  const void* __restrict__ Whh1, const void* __restrict__ bhh1,
                  int* __restrict__ ctl)
{
    const int gbx  = blockIdx.x;
    const int L    = gbx >> 5;           // 0: layer0(+fuse), 1: layer1
    const int bx   = gbx & 31;           // 32-col block
    const int n0   = bx * 32;
    int* flagsA    = ctl + 64;                  // 32 flags, stride 16 ints
    int* flagsSelf = ctl + (L ? 64 + 1024 : 64);
    unsigned short* hB = L ? h2B : h1B;
    const void* Whh  = L ? Whh1 : Whh0;
    const void* bhhv = L ? bhh1 : bhh0;

    __shared__ unsigned short Wl[32 * 1032];              // 66048 B
    __shared__ unsigned short Wn[32 * 1032];              // 66048 B (L0 only)
    __shared__ __align__(16) unsigned short hTile[2048];  // 4 KB
    __shared__ __align__(16) unsigned short pTile[2048];  // 4 KB
    __shared__ int modeSh[4];
    const int tid = threadIdx.x;

    detect_mode256(Whh, tid, modeSh);
    __syncthreads();
    const int mode = (modeSh[0] + modeSh[1] + modeSh[2] + modeSh[3]) > 16;

    if (mode) {
        const float* Wf = (const float*)Whh;
        for (int i = tid; i < 32 * 256; i += 256) {
            int nl = i >> 8, c = i & 255;
            float4 f = *(const float4*)(Wf + ((size_t)(n0 + nl) << 10) + c * 4);
            unsigned short* d = &Wl[nl * 1032 + c * 4];
            d[0] = f2b(f.x); d[1] = f2b(f.y); d[2] = f2b(f.z); d[3] = f2b(f.w);
        }
        if (L == 0) {
            const float* Wg = (const float*)Wih1;
            for (int i = tid; i < 32 * 256; i += 256) {
                int nl = i >> 8, c = i & 255;
                float4 f = *(const float4*)(Wg + ((size_t)(n0 + nl) << 10) + c * 4);
                unsigned short* d = &Wn[nl * 1032 + c * 4];
                d[0] = f2b(f.x); d[1] = f2b(f.y); d[2] = f2b(f.z); d[3] = f2b(f.w);
            }
        }
    } else {
        const unsigned short* Wb = (const unsigned short*)Whh;
        for (int i = tid; i < 32 * 128; i += 256) {
            int nl = i >> 7, c = i & 127;
            *(short8*)&Wl[nl * 1032 + c * 8] =
                *(const short8*)(Wb + ((size_t)(n0 + nl) << 10) + c * 8);
        }
        if (L == 0) {
            const unsigned short* Wg = (const unsigned short*)Wih1;
            for (int i = tid; i < 32 * 128; i += 256) {
                int nl = i >> 7, c = i & 127;
                *(short8*)&Wn[nl * 1032 + c * 8] =
                    *(const short8*)(Wg + ((size_t)(n0 + nl) << 10) + c * 8);
            }
        }
    }
    __syncthreads();

    const int wave = tid >> 6, lane = tid & 63;
    const int quad = lane >> 4, ln = lane & 15;
    const int brow = wave * 16 + ln;
    // two col-tiles: cols n0+ln (ct0) and n0+16+ln (ct1)
    const int nc0 = n0 + ln, nc1 = n0 + 16 + ln;
    const float bvf0 = mode ? ((const float*)bhhv)[nc0]
                            : b2f(((const unsigned short*)bhhv)[nc0]);
    const float bvf1 = mode ? ((const float*)bhhv)[nc1]
                            : b2f(((const unsigned short*)bhhv)[nc1]);
    const float bnf0 = (L == 0)
        ? (mode ? ((const float*)bih1)[nc0]
                : b2f(((const unsigned short*)bih1)[nc0])) : 0.f;
    const float bnf1 = (L == 0)
        ? (mode ? ((const float*)bih1)[nc1]
                : b2f(((const unsigned short*)bih1)[nc1])) : 0.f;
    const int b0 = wave * 16 + quad * 4;
    const unsigned short* wl0 = &Wl[ln * 1032 + quad * 8];
    const unsigned short* wl1 = wl0 + 16 * 1032;
    const unsigned short* wn0 = &Wn[ln * 1032 + quad * 8];
    const unsigned short* wn1 = wn0 + 16 * 1032;
    // per-lane base offset within an h slab: k = kk*32 + quad*8
    const int hoff = (quad >> 1) * 1024 + brow * 16 + (quad & 1) * 8;

    for (int t = 0; t < TT; ++t) {
        const unsigned short* pp0 = preB + (size_t)t * 65536
                                  + (size_t)(2 * bx) * 1024
                                  + (size_t)b0 * 16 + ln;
        const unsigned short* pp1 = pp0 + 1024;
        unsigned int pr[8];
        floatx4 acc0  = {0.f, 0.f, 0.f, 0.f};
        floatx4 acc1  = {0.f, 0.f, 0.f, 0.f};
        floatx4 acc20 = {0.f, 0.f, 0.f, 0.f};
        floatx4 acc21 = {0.f, 0.f, 0.f, 0.f};

        if (L == 0) {
            // pre0[t] written by proj -> plain loads
            pr[0] = pp0[0]; pr[1] = pp0[16]; pr[2] = pp0[32]; pr[3] = pp0[48];
            pr[4] = pp1[0]; pr[5] = pp1[16]; pr[6] = pp1[32]; pr[7] = pp1[48];
            if (t > 0) {
                short8 a[32];
                const unsigned short* hp = hB + (size_t)((t - 1) & 1) * 65536 + hoff;
                #pragma unroll
                for (int kk = 0; kk < 32; ++kk)
                    asm volatile("global_load_dwordx4 %0, %1, off sc1"
                                 : "=v"(a[kk])
                                 : "v"(hp + (size_t)kk * 2048) : "memory");
                WAIT_VM16(16, a);
                #pragma unroll
                for (int kk = 0; kk < 16; ++kk) {
                    short8 b0f = *(const short8*)(wl0 + kk * 32);
                    short8 b1f = *(const short8*)(wl1 + kk * 32);
                    short8 n0f = *(const short8*)(wn0 + kk * 32);
                    short8 n1f = *(const short8*)(wn1 + kk * 32);
                    acc0  = __builtin_amdgcn_mfma_f32_16x16x32_bf16(a[kk], b0f, acc0,  0, 0, 0);
                    acc1  = __builtin_amdgcn_mfma_f32_16x16x32_bf16(a[kk], b1f, acc1,  0, 0, 0);
                    acc20 = __builtin_amdgcn_mfma_f32_16x16x32_bf16(a[kk], n0f, acc20, 0, 0, 0);
                    acc21 = __builtin_amdgcn_mfma_f32_16x16x32_bf16(a[kk], n1f, acc21, 0, 0, 0);
                }
                WAIT_VM16(0, (a + 16));
                #pragma unroll
                for (int kk = 16; kk < 32; ++kk) {
                    short8 b0f = *(const short8*)(wl0 + kk * 32);
                    short8 b1f = *(const short8*)(wl1 + kk * 32);
                    short8 n0f = *(const short8*)(wn0 + kk * 32);
                    short8 n1f = *(const short8*)(wn1 + kk * 32);
                    acc0  = __builtin_amdgcn_mfma_f32_16x16x32_bf16(a[kk], b0f, acc0,  0, 0, 0);
                    acc1  = __builtin_amdgcn_mfma_f32_16x16x32_bf16(a[kk], b1f, acc1,  0, 0, 0);
                    acc20 = __builtin_amdgcn_mfma_f32_16x16x32_bf16(a[kk], n0f, acc20, 0, 0, 0);
                    acc21 = __builtin_amdgcn_mfma_f32_16x16x32_bf16(a[kk], n1f, acc21, 0, 0, 0);
                }
            }
        } else {
            // 1:1 producer wait FIRST (no asm loads live across the spin)
            {
                const int* fp = &flagsA[bx * 16];
                for (;;) {
                    int v;
                    asm volatile("global_load_dword %0, %1, off sc1\n\t"
                                 "s_waitcnt vmcnt(0)"
                                 : "=v"(v) : "v"(fp) : "memory");
                    if (v >= t + 2) break;
                    asm volatile("s_sleep 2");
                }
            }
            if (t > 0) {
                short8 a[32];
                const unsigned short* hp = hB + (size_t)((t - 1) & 1) * 65536 + hoff;
                #pragma unroll
                for (int kk = 0; kk < 32; ++kk)
                    asm volatile("global_load_dwordx4 %0, %1, off sc1"
                                 : "=v"(a[kk])
                                 : "v"(hp + (size_t)kk * 2048) : "memory");
                WAIT_VM16(16, a);
                #pragma unroll
                for (int kk = 0; kk < 16; ++kk) {
                    short8 b0f = *(const short8*)(wl0 + kk * 32);
                    short8 b1f = *(const short8*)(wl1 + kk * 32);
                    acc0 = __builtin_amdgcn_mfma_f32_16x16x32_bf16(a[kk], b0f, acc0, 0, 0, 0);
                    acc1 = __builtin_amdgcn_mfma_f32_16x16x32_bf16(a[kk], b1f, acc1, 0, 0, 0);
                }
                // pre1[t] (sc1, cross-XCD), issued after a[16..31]:
                // vmcnt(8) below completes all 16 older a-loads first.
                asm volatile("global_load_ushort %0, %1, off sc1"
                             : "=v"(pr[0]) : "v"(pp0) : "memory");
                asm volatile("global_load_ushort %0, %1, off offset:32 sc1"
                             : "=v"(pr[1]) : "v"(pp0) : "memory");
                asm volatile("global_load_ushort %0, %1, off offset:64 sc1"
                             : "=v"(pr[2]) : "v"(pp0) : "memory");
                asm volatile("global_load_ushort %0, %1, off offset:96 sc1"
                             : "=v"(pr[3]) : "v"(pp0) : "memory");
                asm volatile("global_load_ushort %0, %1, off sc1"
                             : "=v"(pr[4]) : "v"(pp1) : "memory");
                asm volatile("global_load_ushort %0, %1, off offset:32 sc1"
                             : "=v"(pr[5]) : "v"(pp1) : "memory");
                asm volatile("global_load_ushort %0, %1, off offset:64 sc1"
                             : "=v"(pr[6]) : "v"(pp1) : "memory");
                asm volatile("global_load_ushort %0, %1, off offset:96 sc1"
                             : "=v"(pr[7]) : "v"(pp1) : "memory");
                WAIT_VM16(8, (a + 16));   // a[16..31] done; pr* in flight
                #pragma unroll
                for (int kk = 16; kk < 32; ++kk) {
                    short8 b0f = *(const short8*)(wl0 + kk * 32);
                    short8 b1f = *(const short8*)(wl1 + kk * 32);
                    acc0 = __builtin_amdgcn_mfma_f32_16x16x32_bf16(a[kk], b0f, acc0, 0, 0, 0);
                    acc1 = __builtin_amdgcn_mfma_f32_16x16x32_bf16(a[kk], b1f, acc1, 0, 0, 0);
                }
            } else {
                asm volatile("global_load_ushort %0, %1, off sc1"
                             : "=v"(pr[0]) : "v"(pp0) : "memory");
                asm volatile("global_load_ushort %0, %1, off offset:32 sc1"
                             : "=v"(pr[1]) : "v"(pp0) : "memory");
                asm volatile("global_load_ushort %0, %1, off offset:64 sc1"
                             : "=v"(pr[2]) : "v"(pp0) : "memory");
                asm volatile("global_load_ushort %0, %1, off offset:96 sc1"
                             : "=v"(pr[3]) : "v"(pp0) : "memory");
                asm volatile("global_load_ushort %0, %1, off sc1"
                             : "=v"(pr[4]) : "v"(pp1) : "memory");
                asm volatile("global_load_ushort %0, %1, off offset:32 sc1"
                             : "=v"(pr[5]) : "v"(pp1) : "memory");
                asm volatile("global_load_ushort %0, %1, off offset:64 sc1"
                             : "=v"(pr[6]) : "v"(pp1) : "memory");
                asm volatile("global_load_ushort %0, %1, off offset:96 sc1"
                             : "=v"(pr[7]) : "v"(pp1) : "memory");
            }
            WAIT_PR8(pr);   // bind pr at a real vmcnt(0) just before use
        }

        hTile[(b0 + 0) * 16 + ln]        = f2b(tanhf(acc0[0] + b2f(pr[0]) + bvf0));
        hTile[(b0 + 1) * 16 + ln]        = f2b(tanhf(acc0[1] + b2f(pr[1]) + bvf0));
        hTile[(b0 + 2) * 16 + ln]        = f2b(tanhf(acc0[2] + b2f(pr[2]) + bvf0));
        hTile[(b0 + 3) * 16 + ln]        = f2b(tanhf(acc0[3] + b2f(pr[3]) + bvf0));
        hTile[1024 + (b0 + 0) * 16 + ln] = f2b(tanhf(acc1[0] + b2f(pr[4]) + bvf1));
        hTile[1024 + (b0 + 1) * 16 + ln] = f2b(tanhf(acc1[1] + b2f(pr[5]) + bvf1));
        hTile[1024 + (b0 + 2) * 16 + ln] = f2b(tanhf(acc1[2] + b2f(pr[6]) + bvf1));
        hTile[1024 + (b0 + 3) * 16 + ln] = f2b(tanhf(acc1[3] + b2f(pr[7]) + bvf1));
        if (L == 0 && t > 0) {
            pTile[(b0 + 0) * 16 + ln]        = f2b(acc20[0] + bnf0);
            pTile[(b0 + 1) * 16 + ln]        = f2b(acc20[1] + bnf0);
            pTile[(b0 + 2) * 16 + ln]        = f2b(acc20[2] + bnf0);
            pTile[(b0 + 3) * 16 + ln]        = f2b(acc20[3] + bnf0);
            pTile[1024 + (b0 + 0) * 16 + ln] = f2b(acc21[0] + bnf1);
            pTile[1024 + (b0 + 1) * 16 + ln] = f2b(acc21[1] + bnf1);
            pTile[1024 + (b0 + 2) * 16 + ln] = f2b(acc21[2] + bnf1);
            pTile[1024 + (b0 + 3) * 16 + ln] = f2b(acc21[3] + bnf1);
        }
        __syncthreads();
        {   // 4 KB contiguous (2 kb-blocks) -> full 64B lines; 256 thr x 16B
            short8 hv = *(const short8*)&hTile[tid * 8];
            asm volatile("global_store_dwordx4 %0, %1, off sc1"
                         :: "v"(hB + (size_t)(t & 1) * 65536
                                + (size_t)(2 * bx) * 1024 + tid * 8),
                            "v"(hv) : "memory");
            if (L == 0 && t > 0) {
                short8 pv = *(const short8*)&pTile[tid * 8];
                asm volatile("global_store_dwordx4 %0, %1, off sc1"
                             :: "v"(preB + (size_t)(t - 1) * 65536
                                    + (size_t)(2 * bx) * 1024 + tid * 8),
                                "v"(pv) : "memory");
            }
        }
        if (t < TT - 1) {
            asm volatile("s_waitcnt vmcnt(0)" ::: "memory");
            __syncthreads();
            if (tid == 0) {
                int tv = t + 1;
                asm volatile("global_store_dword %0, %1, off sc1"
                             :: "v"(&flagsSelf[bx * 16]), "v"(tv) : "memory");
            }
            if (tid < 64) {   // 32 group flags; lanes >=32 idle-high
                for (;;) {
                    int v = 0x7fffffff;
                    if (tid < 32) {
                        asm volatile("global_load_dword %0, %1, off sc1\n\t"
                                     "s_waitcnt vmcnt(0)"
                                     : "=v"(v) : "v"(&flagsSelf[tid * 16]) : "memory");
                    }
                    if (!__any(v < t + 1)) break;
                    asm volatile("s_sleep 1");
                }
            }
            __syncthreads();
        }
    }

    if (L == 0) {   // tail: pre1[511] needs full h1[511]
        asm volatile("s_waitcnt vmcnt(0)" ::: "memory");
        __syncthreads();
        if (tid == 0) {
            int tv = TT;   // releases layer-1 t=510
            asm volatile("global_store_dword %0, %1, off sc1"
                         :: "v"(&flagsSelf[bx * 16]), "v"(tv) : "memory");
        }
        if (tid < 64) {
            for (;;) {
                int v = 0x7fffffff;
                if (tid < 32) {
                    asm volatile("global_load_dword %0, %1, off sc1\n\t"
                                 "s_waitcnt vmcnt(0)"
                                 : "=v"(v) : "v"(&flagsSelf[tid * 16]) : "memory");
                }
                if (!__any(v < TT)) break;
                asm volatile("s_sleep 1");
            }
        }
        __syncthreads();

        const unsigned short* hp = hB + (size_t)((TT - 1) & 1) * 65536 + hoff;
        short8 a[32];
        floatx4 acc20 = {0.f, 0.f, 0.f, 0.f};
        floatx4 acc21 = {0.f, 0.f, 0.f, 0.f};
        #pragma unroll
        for (int kk = 0; kk < 32; ++kk)
            asm volatile("global_load_dwordx4 %0, %1, off sc1"
                         : "=v"(a[kk])
                         : "v"(hp + (size_t)kk * 2048) : "memory");
        WAIT_VM16(16, a);
        #pragma unroll
        for (int kk = 0; kk < 16; ++kk) {
            short8 n0f = *(const short8*)(wn0 + kk * 32);
            short8 n1f = *(const short8*)(wn1 + kk * 32);
            acc20 = __builtin_amdgcn_mfma_f32_16x16x32_bf16(a[kk], n0f, acc20, 0, 0, 0);
            acc21 = __builtin_amdgcn_mfma_f32_16x16x32_bf16(a[kk], n1f, acc21, 0, 0, 0);
        }
        WAIT_VM16(0, (a + 16));
        #pragma unroll
        for (int kk = 16; kk < 32; ++kk) {
            short8 n0f = *(const short8*)(wn0 + kk * 32);
            short8 n1f = *(const short8*)(wn1 + kk * 32);
            acc20 = __builtin_amdgcn_mfma_f32_16x16x32_bf16(a[kk], n0f, acc20, 0, 0, 0);
            acc21 = __builtin_amdgcn_mfma_f32_16x16x32_bf16(a[kk], n1f, acc21, 0, 0, 0);
        }
        pTile[(b0 + 0) * 16 + ln]        = f2b(acc20[0] + bnf0);
        pTile[(b0 + 1) * 16 + ln]        = f2b(acc20[1] + bnf0);
        pTile[(b0 + 2) * 16 + ln]        = f2b(acc20[2] + bnf0);
        pTile[(b0 + 3) * 16 + ln]        = f2b(acc20[3] + bnf0);
        pTile[1024 + (b0 + 0) * 16 + ln] = f2b(acc21[0] + bnf1);
        pTile[1024 + (b0 + 1) * 16 + ln] = f2b(acc21[1] + bnf1);
        pTile[1024 + (b0 + 2) * 16 + ln] = f2b(acc21[2] + bnf1);
        pTile[1024 + (b0 + 3) * 16 + ln] = f2b(acc21[3] + bnf1);
        __syncthreads();
        {
            short8 pv = *(const short8*)&pTile[tid * 8];
            asm volatile("global_store_dwordx4 %0, %1, off sc1"
                         :: "v"(preB + (size_t)(TT - 1) * 65536
                                + (size_t)(2 * bx) * 1024 + tid * 8),
                            "v"(pv) : "memory");
        }
        asm volatile("s_waitcnt vmcnt(0)" ::: "memory");
        __syncthreads();
        if (tid == 0) {
            int tv = TT + 1;   // releases layer-1 t=511
            asm volatile("global_store_dword %0, %1, off sc1"
                         :: "v"(&flagsSelf[bx * 16]), "v"(tv) : "memory");
        }
    }
}

// ---------------------------------------------------------------------------
// fc: out[b] = sigmoid(dot(h2[T-1][b], Wfc) + bfc) -- h2 ring slab (TT-1)&1
// Mode detected from WhhD (Whh1: >=2048 shorts in either dtype).
// ---------------------------------------------------------------------------
__global__ __launch_bounds__(1024)
void fc_kernel(const unsigned short* __restrict__ h,
               const void* __restrict__ Wfc,
               const void* __restrict__ bfc,
               const void* __restrict__ WhhD,
               float* __restrict__ out)
{
    const int tid = threadIdx.x;
    __shared__ int modeSh[16];
    {
        const unsigned short* p = (const unsigned short*)WhhD;
        int bad = 0;
        if (tid < 1024) {
            float v = b2f(p[2 * tid]);
            if (!(v > -0.5f && v < 0.5f)) bad++;
        }
        for (int off = 32; off; off >>= 1) bad += __shfl_down(bad, off);
        if ((tid & 63) == 0) modeSh[tid >> 6] = bad;
    }
    __syncthreads();
    int modeSum = 0;
    for (int w = 0; w < 16; ++w) modeSum += modeSh[w];
    const int mode = modeSum > 16;

    const int b = tid >> 4, sub = tid & 15;
    const unsigned short* hr = h + (size_t)((TT - 1) & 1) * 65536 + b * 16 + sub;
    float s = 0.f;
    for (int j = 0; j < 64; ++j) {          // k = j*16 + sub
        float w = mode ? ((const float*)Wfc)[j * 16 + sub]
                       : b2f(((const unsigned short*)Wfc)[j * 16 + sub]);
        s += b2f(hr[(size_t)j * 1024]) * w;
    }
    for (int off = 8; off; off >>= 1)
        s += __shfl_down(s, off, 16);
    if (sub == 0) {
        float bv = mode ? ((const float*)bfc)[0]
                        : b2f(((const unsigned short*)bfc)[0]);
        out[b] = 1.f / (1.f + expf(-(s + bv)));
    }
}

// ---------------------------------------------------------------------------
extern "C" void kernel_launch(void* const* d_in, const int* in_sizes, int n_in,
                              void* d_out, int out_size, void* d_ws, size_t ws_size,
                              hipStream_t stream)
{
    const int*  x    = (const int*)d_in[0];
    const void* emb  = d_in[1];
    const void* Wih0 = d_in[2];
    const void* Whh0 = d_in[3];
    const void* bih0 = d_in[4];
    const void* bhh0 = d_in[5];
    const void* Wih1 = d_in[6];
    const void* Whh1 = d_in[7];
    const void* bih1 = d_in[8];
    const void* bhh1 = d_in[9];
    const void* Wfc  = d_in[10];
    const void* bfc  = d_in[11];
    float* out = (float*)d_out;

    char* ws = (char*)d_ws;
    int*            ctl  = (int*)ws;                              // 16 KiB (flags @64B stride)
    unsigned short* pre  = (unsigned short*)(ws + 16384);         // 64 MiB
    unsigned short* h1   = (unsigned short*)(ws + 16384 + (size_t)67108864); // 256 KiB ring
    unsigned short* h2   = h1 + 2 * 65536;                        // 256 KiB ring

    // layer 0 input projection (one WG per t; emb staged once; WG0 zeroes flags)
    proj_kernel<<<dim3(512), dim3(256), 0, stream>>>(
        x, emb, Wih0, bih0, pre, ctl);
    // both recurrences, software-pipelined; 32 cols per WG (64 WGs)
    scan2_kernel<<<dim3(64), dim3(256), 0, stream>>>(
        pre, h1, h2, Whh0, bhh0, Wih1, bih1, Whh1, bhh1, ctl);
    // final FC + sigmoid
    fc_kernel<<<dim3(1), dim3(1024), 0, stream>>>(h2, Wfc, bfc, Whh1, out);
}